// Round 1
// baseline (1491.999 us; speedup 1.0000x reference)
//
#include <hip/hip_runtime.h>
#include <math.h>

// Problem constants
#define NN 118   // nodes
#define EE 372   // edges
#define GG 2048  // B*T
#define DD 128   // hidden
#define TT 256   // seq len
#define BB 8     // batch
#define FD 512   // 4*D

__device__ __forceinline__ float sigmoidf_(float x) { return 1.0f / (1.0f + expf(-x)); }
__device__ __forceinline__ float siluf_(float x) { return x / (1.0f + expf(-x)); }

// ---------------------------------------------------------------------------
// prep: degree / CSR-by-dst / edge coeffs / fused biases. 1 block.
// Auto-detects whether edge_index arrived as int64 (odd int32 words all zero)
// or int32. Indices clamped so a wrong guess can't fault.
// ---------------------------------------------------------------------------
__global__ void prep_kernel(const int* __restrict__ ei,
                            const float* __restrict__ bih0, const float* __restrict__ bhh0,
                            const float* __restrict__ bih1, const float* __restrict__ bhh1,
                            float* __restrict__ dinv, float* __restrict__ coeff,
                            float* __restrict__ bias0, float* __restrict__ bias1,
                            int* __restrict__ rowptr, int* __restrict__ colw) {
    __shared__ int sflag;
    __shared__ int ssrc[EE], sdst[EE];
    __shared__ int scount[NN], scur[NN];
    __shared__ int srow[NN + 1];
    __shared__ float sinv[NN];
    int tid = threadIdx.x;
    if (tid == 0) sflag = 0;
    __syncthreads();
    // safe: only first 2*EE int32 words inspected (valid in both layouts)
    for (int i = tid; i < 2 * EE; i += blockDim.x)
        if ((i & 1) && ei[i] != 0) atomicOr(&sflag, 1);
    __syncthreads();
    bool m64 = (sflag == 0);
    for (int e = tid; e < EE; e += blockDim.x) {
        int s, d;
        if (m64) { s = ei[2 * e]; d = ei[2 * EE + 2 * e]; }
        else     { s = ei[e];     d = ei[EE + e]; }
        s = min(max(s, 0), NN - 1); d = min(max(d, 0), NN - 1);
        ssrc[e] = s; sdst[e] = d;
    }
    for (int n = tid; n < NN; n += blockDim.x) { scount[n] = 0; scur[n] = 0; }
    __syncthreads();
    for (int e = tid; e < EE; e += blockDim.x) atomicAdd(&scount[sdst[e]], 1);
    __syncthreads();
    if (tid == 0) {
        srow[0] = 0;
        for (int n = 0; n < NN; ++n) srow[n + 1] = srow[n] + scount[n];
    }
    __syncthreads();
    for (int n = tid; n < NN; n += blockDim.x) {
        float deg = 1.0f + (float)scount[n];
        sinv[n] = rsqrtf(deg);
        dinv[n] = 1.0f / deg;
        rowptr[n] = srow[n];
    }
    if (tid == 0) rowptr[NN] = srow[NN];
    __syncthreads();
    for (int e = tid; e < EE; e += blockDim.x) {
        int dn = sdst[e];
        int pos = srow[dn] + atomicAdd(&scur[dn], 1);
        colw[pos] = ssrc[e];
        coeff[pos] = sinv[ssrc[e]] * sinv[dn];
    }
    for (int j = tid; j < FD; j += blockDim.x) {
        bias0[j] = bih0[j] + bhh0[j];
        bias1[j] = bih1[j] + bhh1[j];
    }
}

// ---------------------------------------------------------------------------
// transpose (512,128) -> (128,512) so the projection GEMM reads coalesced
// ---------------------------------------------------------------------------
__global__ void transpose_kernel(const float* __restrict__ in, float* __restrict__ out) {
    int idx = blockIdx.x * blockDim.x + threadIdx.x;  // 65536 total
    int j = idx >> 7, k = idx & 127;
    out[k * FD + j] = in[idx];
}

// ---------------------------------------------------------------------------
// GCN: one block per graph, 3 layers fused in LDS (132 KB), mean epilogue.
// xb/hb padded to 128 rows (pad rows kept zero) so the tiled matmul needs no
// bounds checks.
// ---------------------------------------------------------------------------
__device__ __forceinline__ void gcn_aggregate(const float* __restrict__ hb, float* __restrict__ xb,
                                              const float* __restrict__ bias,
                                              const float* __restrict__ dinv,
                                              const int* __restrict__ rowptr,
                                              const int* __restrict__ colw,
                                              const float* __restrict__ coeff, int tid) {
    for (int i = tid; i < NN * DD; i += 512) {
        int n = i >> 7, d = i & 127;
        float v = hb[i] * dinv[n];
        int e0 = rowptr[n], e1 = rowptr[n + 1];
        for (int e = e0; e < e1; ++e) v += hb[(colw[e] << 7) + d] * coeff[e];
        v += bias[d];
        xb[i] = siluf_(v);
    }
}

__device__ __forceinline__ void gcn_matmul(const float* __restrict__ xb, float* __restrict__ hb,
                                           const float* __restrict__ W, int tid) {
    // 512 threads: thread covers 4 consecutive d (dq) x 8 rows (ng + 16*i)
    int dq = tid & 31, ng = tid >> 5;
    const float4* W4 = (const float4*)W;
    float acc[32];
#pragma unroll
    for (int i = 0; i < 32; ++i) acc[i] = 0.f;
    for (int k = 0; k < DD; ++k) {
        float4 wv = W4[(k << 5) + dq];
#pragma unroll
        for (int i = 0; i < 8; ++i) {
            float xv = xb[((ng + (i << 4)) << 7) + k];
            acc[4 * i + 0] += xv * wv.x;
            acc[4 * i + 1] += xv * wv.y;
            acc[4 * i + 2] += xv * wv.z;
            acc[4 * i + 3] += xv * wv.w;
        }
    }
    float4* hb4 = (float4*)hb;
#pragma unroll
    for (int i = 0; i < 8; ++i)
        hb4[((ng + (i << 4)) << 5) + dq] = make_float4(acc[4 * i], acc[4 * i + 1], acc[4 * i + 2], acc[4 * i + 3]);
}

__global__ __launch_bounds__(512) void gcn_kernel(
    const float* __restrict__ xg, const float* __restrict__ scale, const float* __restrict__ shift,
    const float* __restrict__ W1, const float* __restrict__ b1,
    const float* __restrict__ W2, const float* __restrict__ b2,
    const float* __restrict__ W3, const float* __restrict__ b3,
    const float* __restrict__ dinv, const int* __restrict__ rowptr,
    const int* __restrict__ colw, const float* __restrict__ coeff,
    float* __restrict__ emb) {
    extern __shared__ float smem[];
    float* xb = smem;            // 128x128
    float* hb = smem + 16384;    // 128x128
    float* xin = smem + 32768;   // 118*3 (+pad)
    int tid = threadIdx.x;
    int g = blockIdx.x;
    // zero the pad rows of xb once; nothing ever writes them again
    for (int i = NN * DD + tid; i < 16384; i += 512) xb[i] = 0.0f;
    float s0 = scale[0], s1 = scale[1], s2 = scale[2];
    float t0 = shift[0], t1 = shift[1], t2 = shift[2];
    const float* xrow = xg + (size_t)g * (NN * 3);
    for (int i = tid; i < NN * 3; i += 512) {
        int f = i % 3;
        float sc = (f == 0) ? s0 : ((f == 1) ? s1 : s2);
        float sf = (f == 0) ? t0 : ((f == 1) ? t1 : t2);
        xin[i] = xrow[i] * sc + sf;
    }
    __syncthreads();
    // layer 1 (K=3)
    for (int i = tid; i < NN * DD; i += 512) {
        int n = i >> 7, d = i & 127;
        const float* xr = xin + n * 3;
        hb[i] = xr[0] * W1[d] + xr[1] * W1[DD + d] + xr[2] * W1[2 * DD + d];
    }
    __syncthreads();
    gcn_aggregate(hb, xb, b1, dinv, rowptr, colw, coeff, tid);
    __syncthreads();
    // layer 2
    gcn_matmul(xb, hb, W2, tid);
    __syncthreads();
    gcn_aggregate(hb, xb, b2, dinv, rowptr, colw, coeff, tid);
    __syncthreads();
    // layer 3
    gcn_matmul(xb, hb, W3, tid);
    __syncthreads();
    gcn_aggregate(hb, xb, b3, dinv, rowptr, colw, coeff, tid);
    __syncthreads();
    // mean over nodes
    if (tid < DD) {
        float s = 0.f;
        for (int n = 0; n < NN; ++n) s += xb[(n << 7) + tid];
        emb[(size_t)g * DD + tid] = s * (1.0f / NN);
    }
}

// ---------------------------------------------------------------------------
// proj: dst[g][j] = bias[j] + sum_k src[g][k] * WT[k][j]   (WT coalesced in j)
// ---------------------------------------------------------------------------
__global__ __launch_bounds__(512) void proj_kernel(const float* __restrict__ src,
                                                   const float* __restrict__ WT,
                                                   const float* __restrict__ bias,
                                                   float* __restrict__ dst) {
    __shared__ __align__(16) float eL[DD];
    int g = blockIdx.x, tid = threadIdx.x;
    if (tid < DD) eL[tid] = src[(size_t)g * DD + tid];
    __syncthreads();
    float acc = bias[tid];
    const float* wt = WT + tid;
#pragma unroll 8
    for (int k = 0; k < DD; ++k) acc += eL[k] * wt[(size_t)k * FD];
    dst[(size_t)g * FD + tid] = acc;
}

// ---------------------------------------------------------------------------
// LSTM scan: one workgroup per batch element (no inter-WG sync).
// Whh row j register-resident (128 VGPRs/thread, 512 thr = 8 waves = 2/EU).
// Input projections precomputed by proj_kernel.
// ---------------------------------------------------------------------------
__global__ __launch_bounds__(512, 2) void scan_kernel(const float* __restrict__ inp,
                                                      const float* __restrict__ Whh,
                                                      float* __restrict__ hseq) {
    __shared__ __align__(16) float sh[DD];
    __shared__ float sc_[DD];
    __shared__ float sg[FD];
    int b = blockIdx.x, j = threadIdx.x;
    float4 wreg[32];
    const float4* wp = ((const float4*)Whh) + (size_t)j * 32;
#pragma unroll
    for (int q = 0; q < 32; ++q) wreg[q] = wp[q];
    if (j < DD) { sh[j] = 0.f; sc_[j] = 0.f; }
    __syncthreads();
    const float* ib = inp + (size_t)b * TT * FD;
    float* hb_ = hseq + (size_t)b * TT * DD;
    for (int t = 0; t < TT; ++t) {
        float gj = ib[t * FD + j];
        const float4* h4 = (const float4*)sh;
        float a0 = 0.f, a1 = 0.f, a2 = 0.f, a3 = 0.f;
#pragma unroll
        for (int q = 0; q < 32; ++q) {
            float4 hv = h4[q];
            a0 += hv.x * wreg[q].x;
            a1 += hv.y * wreg[q].y;
            a2 += hv.z * wreg[q].z;
            a3 += hv.w * wreg[q].w;
        }
        sg[j] = gj + ((a0 + a1) + (a2 + a3));
        __syncthreads();
        if (j < DD) {
            float iv = sigmoidf_(sg[j]);
            float fv = sigmoidf_(sg[DD + j]);
            float gv = tanhf(sg[2 * DD + j]);
            float ov = sigmoidf_(sg[3 * DD + j]);
            float cn = fv * sc_[j] + iv * gv;
            float hn = ov * tanhf(cn);
            sc_[j] = cn;
            sh[j] = hn;
            hb_[t * DD + j] = hn;
        }
        __syncthreads();
    }
}

// ---------------------------------------------------------------------------
// head MLP on final hidden state. 1 block.
// ---------------------------------------------------------------------------
__global__ void head_kernel(const float* __restrict__ h1seq,
                            const float* __restrict__ hW1, const float* __restrict__ hb1,
                            const float* __restrict__ hW2, const float* __restrict__ hb2,
                            const float* __restrict__ hW3, const float* __restrict__ hb3,
                            float* __restrict__ out) {
    __shared__ float fh[BB * DD];
    __shared__ float y1[BB * DD];
    __shared__ float y2[BB * 64];
    int tid = threadIdx.x;
    for (int i = tid; i < BB * DD; i += 256) {
        int bb = i >> 7, d = i & 127;
        fh[i] = h1seq[((size_t)bb * TT + (TT - 1)) * DD + d];
    }
    __syncthreads();
    for (int i = tid; i < BB * DD; i += 256) {
        int bb = i >> 7, jj = i & 127;
        float acc = hb1[jj];
        for (int k = 0; k < DD; ++k) acc += fh[(bb << 7) + k] * hW1[(k << 7) + jj];
        y1[i] = siluf_(acc);
    }
    __syncthreads();
    for (int i = tid; i < BB * 64; i += 256) {
        int bb = i >> 6, jj = i & 63;
        float acc = hb2[jj];
        for (int k = 0; k < DD; ++k) acc += y1[(bb << 7) + k] * hW2[(k << 6) + jj];
        y2[i] = siluf_(acc);
    }
    __syncthreads();
    if (tid < BB * 2) {
        int bb = tid >> 1, m = tid & 1;
        float acc = hb3[m];
        for (int k = 0; k < 64; ++k) acc += y2[(bb << 6) + k] * hW3[k * 2 + m];
        float sp = fmaxf(acc, 0.f) + log1pf(expf(-fabsf(acc)));
        out[tid] = sp + 1e-6f;
    }
}

// ---------------------------------------------------------------------------
extern "C" void kernel_launch(void* const* d_in, const int* in_sizes, int n_in,
                              void* d_out, int out_size, void* d_ws, size_t ws_size,
                              hipStream_t stream) {
    const float* snap  = (const float*)d_in[0];
    const int*   edges = (const int*)d_in[1];
    const float* scale = (const float*)d_in[2];
    const float* shift = (const float*)d_in[3];
    const float* W1 = (const float*)d_in[4];
    const float* b1 = (const float*)d_in[5];
    const float* W2 = (const float*)d_in[6];
    const float* b2 = (const float*)d_in[7];
    const float* W3 = (const float*)d_in[8];
    const float* b3 = (const float*)d_in[9];
    const float* Wih0 = (const float*)d_in[10];
    const float* Whh0 = (const float*)d_in[11];
    const float* bih0 = (const float*)d_in[12];
    const float* bhh0 = (const float*)d_in[13];
    const float* Wih1 = (const float*)d_in[14];
    const float* Whh1 = (const float*)d_in[15];
    const float* bih1 = (const float*)d_in[16];
    const float* bhh1 = (const float*)d_in[17];
    const float* hW1 = (const float*)d_in[18];
    const float* hb1 = (const float*)d_in[19];
    const float* hW2 = (const float*)d_in[20];
    const float* hb2 = (const float*)d_in[21];
    const float* hW3 = (const float*)d_in[22];
    const float* hb3 = (const float*)d_in[23];

    // workspace carve (floats); total ~7.9 MB
    float* ws = (float*)d_ws;
    float* dinv  = ws + 0;       // 128
    float* coeff = ws + 128;     // 384
    float* bias0 = ws + 512;     // 512
    float* bias1 = ws + 1024;    // 512
    int*   rowptr = (int*)(ws + 1536);  // 128
    int*   colw   = (int*)(ws + 1664);  // 384
    float* WT0 = ws + 2048;      // 65536
    float* WT1 = ws + 67584;     // 65536
    float* emb = ws + 133120;    // 262144
    float* inp = ws + 395264;    // 1048576 (reused for both LSTM layers)
    float* h0seq = ws + 1443840; // 262144
    float* h1seq = ws + 1705984; // 262144

    const int smem_gcn = (16384 * 2 + 356) * 4;  // 132,496 B
    hipFuncSetAttribute((const void*)gcn_kernel,
                        hipFuncAttributeMaxDynamicSharedMemorySize, smem_gcn);

    prep_kernel<<<1, 256, 0, stream>>>(edges, bih0, bhh0, bih1, bhh1,
                                       dinv, coeff, bias0, bias1, rowptr, colw);
    transpose_kernel<<<128, 512, 0, stream>>>(Wih0, WT0);
    transpose_kernel<<<128, 512, 0, stream>>>(Wih1, WT1);
    gcn_kernel<<<GG, 512, smem_gcn, stream>>>(snap, scale, shift, W1, b1, W2, b2, W3, b3,
                                              dinv, rowptr, colw, coeff, emb);
    proj_kernel<<<GG, 512, 0, stream>>>(emb, WT0, bias0, inp);
    scan_kernel<<<BB, 512, 0, stream>>>(inp, Whh0, h0seq);
    proj_kernel<<<GG, 512, 0, stream>>>(h0seq, WT1, bias1, inp);
    scan_kernel<<<BB, 512, 0, stream>>>(inp, Whh1, h1seq);
    head_kernel<<<1, 256, 0, stream>>>(h1seq, hW1, hb1, hW2, hb2, hW3, hb3, (float*)d_out);
}

// Round 2
// 844.257 us; speedup vs baseline: 1.7672x; 1.7672x over previous
//
#include <hip/hip_runtime.h>
#include <math.h>

// Problem constants
#define NN 118   // nodes
#define EE 372   // edges
#define GG 2048  // B*T
#define DD 128   // hidden
#define TT 256   // seq len
#define BB 8     // batch
#define FD 512   // 4*D

// LDS strides (padded to keep MFMA frag loads / C writeback at <=2-way bank aliasing)
#define XS 136   // xb/wt row stride in bf16 elems (272 B = 17*16, 16B-aligned rows)
#define HS 130   // hb row stride in f32 (even -> aligned float2)

typedef short bf16x8 __attribute__((ext_vector_type(8)));
typedef float f32x4  __attribute__((ext_vector_type(4)));

__device__ __forceinline__ float frcp_(float x) { return __builtin_amdgcn_rcpf(x); }
__device__ __forceinline__ float sig_f(float x) { return frcp_(1.0f + __expf(-x)); }
__device__ __forceinline__ float tanh_f(float x) { return 1.0f - 2.0f * frcp_(__expf(2.0f * x) + 1.0f); }
__device__ __forceinline__ float silu_f(float x) { return x * frcp_(1.0f + __expf(-x)); }
__device__ __forceinline__ float sigmoidf_(float x) { return 1.0f / (1.0f + expf(-x)); }
__device__ __forceinline__ float siluf_(float x) { return x / (1.0f + expf(-x)); }

__device__ __forceinline__ unsigned short f2bf(float x) {
    unsigned int u = __float_as_uint(x);
    unsigned int r = (u + 0x7fffu + ((u >> 16) & 1u)) >> 16;
    return (unsigned short)r;
}
__device__ __forceinline__ float bf2f(unsigned short b) {
    return __uint_as_float(((unsigned int)b) << 16);
}

// ---------------------------------------------------------------------------
// prep: degree / CSR-by-dst / edge coeffs / fused biases. 1 block.
// ---------------------------------------------------------------------------
__global__ void prep_kernel(const int* __restrict__ ei,
                            const float* __restrict__ bih0, const float* __restrict__ bhh0,
                            const float* __restrict__ bih1, const float* __restrict__ bhh1,
                            float* __restrict__ dinv, float* __restrict__ coeff,
                            float* __restrict__ bias0, float* __restrict__ bias1,
                            int* __restrict__ rowptr, int* __restrict__ colw) {
    __shared__ int sflag;
    __shared__ int ssrc[EE], sdst[EE];
    __shared__ int scount[NN], scur[NN];
    __shared__ int srow[NN + 1];
    __shared__ float sinv[NN];
    int tid = threadIdx.x;
    if (tid == 0) sflag = 0;
    __syncthreads();
    for (int i = tid; i < 2 * EE; i += blockDim.x)
        if ((i & 1) && ei[i] != 0) atomicOr(&sflag, 1);
    __syncthreads();
    bool m64 = (sflag == 0);
    for (int e = tid; e < EE; e += blockDim.x) {
        int s, d;
        if (m64) { s = ei[2 * e]; d = ei[2 * EE + 2 * e]; }
        else     { s = ei[e];     d = ei[EE + e]; }
        s = min(max(s, 0), NN - 1); d = min(max(d, 0), NN - 1);
        ssrc[e] = s; sdst[e] = d;
    }
    for (int n = tid; n < NN; n += blockDim.x) { scount[n] = 0; scur[n] = 0; }
    __syncthreads();
    for (int e = tid; e < EE; e += blockDim.x) atomicAdd(&scount[sdst[e]], 1);
    __syncthreads();
    if (tid == 0) {
        srow[0] = 0;
        for (int n = 0; n < NN; ++n) srow[n + 1] = srow[n] + scount[n];
    }
    __syncthreads();
    for (int n = tid; n < NN; n += blockDim.x) {
        float deg = 1.0f + (float)scount[n];
        sinv[n] = rsqrtf(deg);
        dinv[n] = 1.0f / deg;
        rowptr[n] = srow[n];
    }
    if (tid == 0) rowptr[NN] = srow[NN];
    __syncthreads();
    for (int e = tid; e < EE; e += blockDim.x) {
        int dn = sdst[e];
        int pos = srow[dn] + atomicAdd(&scur[dn], 1);
        colw[pos] = ssrc[e];
        coeff[pos] = sinv[ssrc[e]] * sinv[dn];
    }
    for (int j = tid; j < FD; j += blockDim.x) {
        bias0[j] = bih0[j] + bhh0[j];
        bias1[j] = bih1[j] + bhh1[j];
    }
}

// ---------------------------------------------------------------------------
// W (K=128 x N=128, fp32) -> Wt bf16 [n][k] (k contiguous) for MFMA B-frags
// ---------------------------------------------------------------------------
__global__ void convw_kernel(const float* __restrict__ W, unsigned short* __restrict__ out) {
    int i = blockIdx.x * 512 + threadIdx.x;  // 16384 total
    int n = i >> 7, k = i & 127;
    out[i] = f2bf(W[k * DD + n]);
}

// ---------------------------------------------------------------------------
// transpose (512,128) -> (128,512) so the projection GEMM reads coalesced
// ---------------------------------------------------------------------------
__global__ void transpose_kernel(const float* __restrict__ in, float* __restrict__ out) {
    int idx = blockIdx.x * blockDim.x + threadIdx.x;  // 65536 total
    int j = idx >> 7, k = idx & 127;
    out[k * FD + j] = in[idx];
}

// ---------------------------------------------------------------------------
// GCN building blocks
// ---------------------------------------------------------------------------
__device__ __forceinline__ void load_wt(const unsigned short* __restrict__ Wtg,
                                        unsigned short* __restrict__ wt, int tid) {
    const ushort4* src = (const ushort4*)Wtg;  // 4096 8-byte chunks
    for (int c = tid; c < 4096; c += 512) {
        int n = c >> 5, kq = c & 31;
        ushort4 v = src[c];
        *(ushort4*)(wt + n * XS + kq * 4) = v;
    }
}

// aggregate: read fp32 h (hb), GCN-normalized scatter-sum + bias + silu,
// write bf16 into xb (MFMA A-layout rows). Wave-uniform node per instr.
__device__ __forceinline__ void gcn_aggregate(const float* __restrict__ hb,
                                              unsigned short* __restrict__ xb,
                                              const float* __restrict__ bias,
                                              const float* __restrict__ dinv,
                                              const int* __restrict__ rowptr,
                                              const int* __restrict__ colw,
                                              const float* __restrict__ coeff, int tid) {
    for (int i = tid; i < NN * 64; i += 512) {
        int n = i >> 6, dd = (i & 63) * 2;
        float2 v = *(const float2*)(hb + n * HS + dd);
        float di = dinv[n];
        float a0 = v.x * di, a1 = v.y * di;
        int e0 = rowptr[n], e1 = rowptr[n + 1];
        for (int e = e0; e < e1; ++e) {
            float c = coeff[e];
            int sn = colw[e];
            float2 u = *(const float2*)(hb + sn * HS + dd);
            a0 += u.x * c; a1 += u.y * c;
        }
        a0 = silu_f(a0 + bias[dd]);
        a1 = silu_f(a1 + bias[dd + 1]);
        unsigned int pk = (unsigned int)f2bf(a0) | ((unsigned int)f2bf(a1) << 16);
        *(unsigned int*)(xb + n * XS + dd) = pk;
    }
}

// MFMA matmul: hb(f32,128x128) = xb(bf16) @ Wt^T. 8 waves, each 64x32 tile.
__device__ __forceinline__ void gcn_mfma(const unsigned short* __restrict__ xb,
                                         const unsigned short* __restrict__ wt,
                                         float* __restrict__ hb, int tid) {
    int lane = tid & 63, w = tid >> 6;
    int lm = lane & 15, lq = lane >> 4;
    int wm = (w & 1) * 64;    // row block (64)
    int wn = (w >> 1) * 32;   // col block (32)
    f32x4 acc[4][2];
#pragma unroll
    for (int mt = 0; mt < 4; ++mt)
#pragma unroll
        for (int nt = 0; nt < 2; ++nt)
            acc[mt][nt] = (f32x4){0.f, 0.f, 0.f, 0.f};
#pragma unroll
    for (int kb = 0; kb < 4; ++kb) {
        int ko = kb * 32 + lq * 8;
        bf16x8 bfr0 = *(const bf16x8*)(wt + (wn + lm) * XS + ko);
        bf16x8 bfr1 = *(const bf16x8*)(wt + (wn + 16 + lm) * XS + ko);
#pragma unroll
        for (int mt = 0; mt < 4; ++mt) {
            bf16x8 af = *(const bf16x8*)(xb + (wm + mt * 16 + lm) * XS + ko);
            acc[mt][0] = __builtin_amdgcn_mfma_f32_16x16x32_bf16(af, bfr0, acc[mt][0], 0, 0, 0);
            acc[mt][1] = __builtin_amdgcn_mfma_f32_16x16x32_bf16(af, bfr1, acc[mt][1], 0, 0, 0);
        }
    }
#pragma unroll
    for (int mt = 0; mt < 4; ++mt)
#pragma unroll
        for (int nt = 0; nt < 2; ++nt)
#pragma unroll
            for (int i = 0; i < 4; ++i)
                hb[(wm + mt * 16 + lq * 4 + i) * HS + wn + nt * 16 + lm] = acc[mt][nt][i];
}

__global__ __launch_bounds__(512) void gcn_kernel(
    const float* __restrict__ xg, const float* __restrict__ scale, const float* __restrict__ shift,
    const float* __restrict__ W1, const float* __restrict__ b1,
    const float* __restrict__ b2, const float* __restrict__ b3,
    const unsigned short* __restrict__ Wt2g, const unsigned short* __restrict__ Wt3g,
    const float* __restrict__ dinv, const int* __restrict__ rowptr,
    const int* __restrict__ colw, const float* __restrict__ coeff,
    float* __restrict__ emb) {
    extern __shared__ char smem[];
    unsigned short* xb = (unsigned short*)smem;             // 128*136 bf16 = 34816 B
    unsigned short* wt = (unsigned short*)(smem + 34816);   // 128*136 bf16 = 34816 B
    float* hb = (float*)(smem + 69632);                     // 128*130 f32  = 66560 B
    float* xin = (float*)(smem + 136192);                   // 354 f32
    int tid = threadIdx.x;
    int g = blockIdx.x;

    // phase 0: input (scale/shift) + Wt2 into LDS
    float s0 = scale[0], s1 = scale[1], s2 = scale[2];
    float t0 = shift[0], t1 = shift[1], t2 = shift[2];
    const float* xrow = xg + (size_t)g * (NN * 3);
    for (int i = tid; i < NN * 3; i += 512) {
        int f = i % 3;
        float sc = (f == 0) ? s0 : ((f == 1) ? s1 : s2);
        float sf = (f == 0) ? t0 : ((f == 1) ? t1 : t2);
        xin[i] = xrow[i] * sc + sf;
    }
    load_wt(Wt2g, wt, tid);
    __syncthreads();
    // layer 1 (K=3) -> hb fp32
    for (int i = tid; i < NN * DD; i += 512) {
        int n = i >> 7, d = i & 127;
        const float* xr = xin + n * 3;
        hb[n * HS + d] = xr[0] * W1[d] + xr[1] * W1[DD + d] + xr[2] * W1[2 * DD + d];
    }
    __syncthreads();
    gcn_aggregate(hb, xb, b1, dinv, rowptr, colw, coeff, tid);
    __syncthreads();
    // layer 2
    gcn_mfma(xb, wt, hb, tid);
    __syncthreads();
    load_wt(Wt3g, wt, tid);
    gcn_aggregate(hb, xb, b2, dinv, rowptr, colw, coeff, tid);
    __syncthreads();
    // layer 3
    gcn_mfma(xb, wt, hb, tid);
    __syncthreads();
    gcn_aggregate(hb, xb, b3, dinv, rowptr, colw, coeff, tid);
    __syncthreads();
    // mean over nodes (partials across 4 thread-groups, hb reused as scratch)
    {
        int d = tid & 127, part = tid >> 7;
        int n0 = part * 30;
        int n1 = (n0 + 30 < NN) ? (n0 + 30) : NN;
        float s = 0.f;
        for (int n = n0; n < n1; ++n) s += bf2f(xb[n * XS + d]);
        hb[part * 128 + d] = s;
    }
    __syncthreads();
    if (tid < 128) {
        float s = hb[tid] + hb[128 + tid] + hb[256 + tid] + hb[384 + tid];
        emb[(size_t)g * DD + tid] = s * (1.0f / (float)NN);
    }
}

// ---------------------------------------------------------------------------
// proj: dst[g][j] = bias[j] + sum_k src[g][k] * WT[k][j]   (WT coalesced in j)
// ---------------------------------------------------------------------------
__global__ __launch_bounds__(512) void proj_kernel(const float* __restrict__ src,
                                                   const float* __restrict__ WT,
                                                   const float* __restrict__ bias,
                                                   float* __restrict__ dst) {
    __shared__ __align__(16) float eL[DD];
    int g = blockIdx.x, tid = threadIdx.x;
    if (tid < DD) eL[tid] = src[(size_t)g * DD + tid];
    __syncthreads();
    float acc = bias[tid];
    const float* wt = WT + tid;
#pragma unroll 8
    for (int k = 0; k < DD; ++k) acc += eL[k] * wt[(size_t)k * FD];
    dst[(size_t)g * FD + tid] = acc;
}

// ---------------------------------------------------------------------------
// LSTM scan: one workgroup per batch element. Whh row j register-resident.
// h broadcast via LDS; c stays in registers of threads j<128; activations
// distributed across all 8 waves.
// ---------------------------------------------------------------------------
__global__ __launch_bounds__(512, 2) void scan_kernel(const float* __restrict__ inp,
                                                      const float* __restrict__ Whh,
                                                      float* __restrict__ hseq) {
    __shared__ __align__(16) float sh[DD];
    __shared__ float sg[FD];
    int b = blockIdx.x, j = threadIdx.x;
    float4 wreg[32];
    const float4* wp = ((const float4*)Whh) + (size_t)j * 32;
#pragma unroll
    for (int q = 0; q < 32; ++q) wreg[q] = wp[q];
    float creg = 0.f;
    if (j < DD) sh[j] = 0.f;
    __syncthreads();
    const float* ib = inp + (size_t)b * TT * FD;
    float* hb_ = hseq + (size_t)b * TT * DD;
    bool isg = (j >= 2 * DD) && (j < 3 * DD);
    for (int t = 0; t < TT; ++t) {
        float gj = ib[t * FD + j];
        const float4* h4 = (const float4*)sh;
        float a0 = 0.f, a1 = 0.f, a2 = 0.f, a3 = 0.f;
#pragma unroll
        for (int q = 0; q < 32; ++q) {
            float4 hv = h4[q];
            a0 += hv.x * wreg[q].x;
            a1 += hv.y * wreg[q].y;
            a2 += hv.z * wreg[q].z;
            a3 += hv.w * wreg[q].w;
        }
        float pre = gj + ((a0 + a1) + (a2 + a3));
        sg[j] = isg ? tanh_f(pre) : sig_f(pre);
        __syncthreads();
        if (j < DD) {
            float cn = sg[DD + j] * creg + sg[j] * sg[2 * DD + j];
            creg = cn;
            float hn = sg[3 * DD + j] * tanh_f(cn);
            sh[j] = hn;
            hb_[t * DD + j] = hn;
        }
        __syncthreads();
    }
}

// ---------------------------------------------------------------------------
// head MLP on final hidden state. 1 block.
// ---------------------------------------------------------------------------
__global__ void head_kernel(const float* __restrict__ h1seq,
                            const float* __restrict__ hW1, const float* __restrict__ hb1,
                            const float* __restrict__ hW2, const float* __restrict__ hb2,
                            const float* __restrict__ hW3, const float* __restrict__ hb3,
                            float* __restrict__ out) {
    __shared__ float fh[BB * DD];
    __shared__ float y1[BB * DD];
    __shared__ float y2[BB * 64];
    int tid = threadIdx.x;
    for (int i = tid; i < BB * DD; i += 256) {
        int bb = i >> 7, d = i & 127;
        fh[i] = h1seq[((size_t)bb * TT + (TT - 1)) * DD + d];
    }
    __syncthreads();
    for (int i = tid; i < BB * DD; i += 256) {
        int bb = i >> 7, jj = i & 127;
        float acc = hb1[jj];
        for (int k = 0; k < DD; ++k) acc += fh[(bb << 7) + k] * hW1[(k << 7) + jj];
        y1[i] = siluf_(acc);
    }
    __syncthreads();
    for (int i = tid; i < BB * 64; i += 256) {
        int bb = i >> 6, jj = i & 63;
        float acc = hb2[jj];
        for (int k = 0; k < DD; ++k) acc += y1[(bb << 7) + k] * hW2[(k << 6) + jj];
        y2[i] = siluf_(acc);
    }
    __syncthreads();
    if (tid < BB * 2) {
        int bb = tid >> 1, m = tid & 1;
        float acc = hb3[m];
        for (int k = 0; k < 64; ++k) acc += y2[(bb << 6) + k] * hW3[k * 2 + m];
        float sp = fmaxf(acc, 0.f) + log1pf(expf(-fabsf(acc)));
        out[tid] = sp + 1e-6f;
    }
}

// ---------------------------------------------------------------------------
extern "C" void kernel_launch(void* const* d_in, const int* in_sizes, int n_in,
                              void* d_out, int out_size, void* d_ws, size_t ws_size,
                              hipStream_t stream) {
    const float* snap  = (const float*)d_in[0];
    const int*   edges = (const int*)d_in[1];
    const float* scale = (const float*)d_in[2];
    const float* shift = (const float*)d_in[3];
    const float* W1 = (const float*)d_in[4];
    const float* b1 = (const float*)d_in[5];
    const float* W2 = (const float*)d_in[6];
    const float* b2 = (const float*)d_in[7];
    const float* W3 = (const float*)d_in[8];
    const float* b3 = (const float*)d_in[9];
    const float* Wih0 = (const float*)d_in[10];
    const float* Whh0 = (const float*)d_in[11];
    const float* bih0 = (const float*)d_in[12];
    const float* bhh0 = (const float*)d_in[13];
    const float* Wih1 = (const float*)d_in[14];
    const float* Whh1 = (const float*)d_in[15];
    const float* bih1 = (const float*)d_in[16];
    const float* bhh1 = (const float*)d_in[17];
    const float* hW1 = (const float*)d_in[18];
    const float* hb1 = (const float*)d_in[19];
    const float* hW2 = (const float*)d_in[20];
    const float* hb2 = (const float*)d_in[21];
    const float* hW3 = (const float*)d_in[22];
    const float* hb3 = (const float*)d_in[23];

    // workspace carve (float indices)
    float* ws = (float*)d_ws;
    float* dinv  = ws + 0;        // 128
    float* coeff = ws + 128;      // 384
    float* bias0 = ws + 512;      // 512
    float* bias1 = ws + 1024;     // 512
    int*   rowptr = (int*)(ws + 1536);   // 119 (<128)
    int*   colw   = (int*)(ws + 1664);   // 384
    unsigned short* Wt2g = (unsigned short*)(ws + 2048);   // 16384 bf16 = 8192 f
    unsigned short* Wt3g = (unsigned short*)(ws + 10240);  // 16384 bf16
    float* WT0 = ws + 18432;      // 65536
    float* WT1 = ws + 83968;      // 65536
    float* emb = ws + 149504;     // 262144
    float* inp = ws + 411648;     // 1048576 (reused for both LSTM layers)
    float* h0seq = ws + 1460224;  // 262144
    float* h1seq = ws + 1722368;  // 262144

    const int smem_gcn = 34816 * 2 + 66560 + 1440;  // 137,632 B
    hipFuncSetAttribute((const void*)gcn_kernel,
                        hipFuncAttributeMaxDynamicSharedMemorySize, smem_gcn);

    prep_kernel<<<1, 256, 0, stream>>>(edges, bih0, bhh0, bih1, bhh1,
                                       dinv, coeff, bias0, bias1, rowptr, colw);
    convw_kernel<<<32, 512, 0, stream>>>(W2, Wt2g);
    convw_kernel<<<32, 512, 0, stream>>>(W3, Wt3g);
    transpose_kernel<<<128, 512, 0, stream>>>(Wih0, WT0);
    transpose_kernel<<<128, 512, 0, stream>>>(Wih1, WT1);
    gcn_kernel<<<GG, 512, smem_gcn, stream>>>(snap, scale, shift, W1, b1, b2, b3,
                                              Wt2g, Wt3g, dinv, rowptr, colw, coeff, emb);
    proj_kernel<<<GG, 512, 0, stream>>>(emb, WT0, bias0, inp);
    scan_kernel<<<BB, 512, 0, stream>>>(inp, Whh0, h0seq);
    proj_kernel<<<GG, 512, 0, stream>>>(h0seq, WT1, bias1, inp);
    scan_kernel<<<BB, 512, 0, stream>>>(inp, Whh1, h1seq);
    head_kernel<<<1, 256, 0, stream>>>(h1seq, hW1, hb1, hW2, hb2, hW3, hb3, (float*)d_out);
}